// Round 5
// baseline (163.581 us; speedup 1.0000x reference)
//
#include <hip/hip_runtime.h>

#define NE 32   // electrons
#define NA 8    // atoms
#define DF 4    // dist features
#define KD 8    // kernel dim
#define ED 16   // embedding dim
#define BATCH 4096

// d_ws layout (floats)
#define WS_W1S0 0     // w1[n=0]*log2e   (d*6+a), 24
#define WS_W1S1 24
#define WS_B1S0 48    // wb1*log2e, 6 each
#define WS_B1S1 54
#define WS_B2H0 60    // wb2*log2e - sum_a w2[a][k], 8 each
#define WS_B2H1 68
#define WS_MS0  76    // n=0 same-spin msg vector, 8
#define WS_MA0  84    // n=0 anti-spin msg vector, 8
#define WS_MS   92    // Ms[kp][k] = (ln2*g_w0) @ hs_w1, 8x8
#define WS_MA   156   // Ma[kp][k] = (ln2*g_w0) @ ha_w1, 8x8
#define WS_CS   220   // (X+g_b0)@hs_w1 + hs_b1, 8
#define WS_CA   228
#define WS_GO0  236   // ln2*g_w0 @ orb, 8
#define WS_GO1  244
#define WS_BASE 252   // (X+g_b0+g_b1)@orb, 1

__global__ void omni_setup(const float* __restrict__ X,   const float* __restrict__ w1,
                           const float* __restrict__ wb1, const float* __restrict__ w2,
                           const float* __restrict__ wb2, const float* __restrict__ hs_w,
                           const float* __restrict__ hs_b,const float* __restrict__ ha_w,
                           const float* __restrict__ ha_b,const float* __restrict__ g_w,
                           const float* __restrict__ g_b, const float* __restrict__ orb_w,
                           float* __restrict__ ws)
{
    const int t = threadIdx.x;
    const float L   = 1.4426950408889634f;   // log2(e)
    const float LN2 = 0.6931471805599453f;
    if (t < 48) {                                   // W1s, both n
        ws[t] = w1[t] * L;
    } else if (t < 60) {                            // B1s
        ws[t] = wb1[t - 48] * L;
    } else if (t < 76) {                            // B2h
        const int u = t - 60, n = u >> 3, k = u & 7;
        float sw = 0.f;
        for (int a = 0; a < 6; ++a) sw += w2[n * 48 + a * KD + k];
        ws[t] = wb2[n * KD + k] * L - sw;
    } else if (t < 92) {                            // ms0 / ma0
        const int u = t - 76, tab = u >> 3, k = u & 7;
        const float* mw = tab ? ha_w : hs_w;        // n=0 slice
        const float* mb = tab ? ha_b : hs_b;
        float acc = mb[k];
        for (int c = 0; c < ED; ++c) acc += X[c] * mw[c * KD + k];
        ws[t] = acc;
    } else if (t < 220) {                           // Ms / Ma (8x8)
        int u = t - 92; const int tab = u >> 6; u &= 63;
        const int kp = u >> 3, k = u & 7;
        const float* mw = (tab ? ha_w : hs_w) + ED * KD;   // n=1 slice
        float acc = 0.f;
        for (int c = 0; c < ED; ++c)
            acc += LN2 * g_w[kp * ED + c] * mw[c * KD + k]; // g_w n=0 slice
        ws[t] = acc;
    } else if (t < 236) {                           // Cs / Ca
        const int u = t - 220, tab = u >> 3, k = u & 7;
        const float* mw = (tab ? ha_w : hs_w) + ED * KD;
        const float* mb = (tab ? ha_b : hs_b) + KD;
        float acc = mb[k];
        for (int c = 0; c < ED; ++c) acc += (X[c] + g_b[c]) * mw[c * KD + k];
        ws[t] = acc;
    } else if (t < 252) {                           // go0 / go1
        const int u = t - 236, n = u >> 3, k = u & 7;
        float acc = 0.f;
        for (int c = 0; c < ED; ++c)
            acc += LN2 * g_w[n * KD * ED + k * ED + c] * orb_w[c];
        ws[t] = acc;
    } else if (t == 252) {                          // base
        float acc = 0.f;
        for (int c = 0; c < ED; ++c) acc += (X[c] + g_b[c] + g_b[ED + c]) * orb_w[c];
        ws[t] = acc;
    }
}

// trans stage only: r[a] = log2(1 + 2^(e@W1s + B1s))
__device__ __forceinline__ void wnet_r(const float4 e,
                                       const float* __restrict__ vB1s,
                                       const float* __restrict__ sW1,
                                       float* __restrict__ r)
{
    #pragma unroll
    for (int a = 0; a < 6; ++a) {
        float u = fmaf(e.x, sW1[a], vB1s[a]);
        u = fmaf(e.y, sW1[6 + a], u);
        u = fmaf(e.z, sW1[12 + a], u);
        u = fmaf(e.w, sW1[18 + a], u);
        r[a] = __builtin_amdgcn_logf(__builtin_amdgcn_exp2f(u) + 1.0f);
    }
}

__device__ __forceinline__ void proj(const float* __restrict__ r,
                                     const float* __restrict__ sW2,
                                     const float* __restrict__ vB2h,
                                     float* __restrict__ racc)
{
    #pragma unroll
    for (int k = 0; k < KD; ++k) {
        float acc = fmaf(r[0], sW2[k], vB2h[k]);
        #pragma unroll
        for (int a = 1; a < 6; ++a) acc = fmaf(r[a], sW2[a * KD + k], acc);
        racc[k] = acc;
    }
}

__global__ __launch_bounds__(256, 6) void omni_main(
    const float* __restrict__ dists_nuc,   // (B, NE, NA, DF)
    const float* __restrict__ dists_elec,  // (B, NE, NE, DF)
    const float* __restrict__ Y,           // (NA, KD)
    const float* __restrict__ w2,          // (2, 6, KD)
    const float* __restrict__ ws,          // precomputed constants
    float* __restrict__ out)               // (B,)
{
    const int tid  = threadIdx.x;
    const int el   = tid >> 7;          // batch-elem slot in block (0,1)
    const int h    = (tid >> 6) & 1;    // wave within elem: electrons of spin h
    const int lane = tid & 63;
    const int il   = lane & 15;
    const int jh   = lane >> 4;         // j quarter (j in [8jh, 8jh+8))
    const int ig   = 16 * h + il;       // this lane's electron
    const int b    = blockIdx.x * 2 + el;
    const int sj   = jh >> 1;           // spin of j range
    const bool same = (sj == h);
    const int t32  = same ? 0 : 32;

    __shared__ float msg[2][65][KD];    // n=1 tables; row 64 = zeros
    __shared__ float part[2][2];
    if (tid < 16) msg[tid >> 3][64][tid & 7] = 0.0f;

    // ---- register-cache distances (reused by both interactions) ----
    const float* de = dists_elec + (((size_t)b * NE + ig) * NE + 8 * jh) * DF;
    const float* dn = dists_nuc  + (((size_t)b * NE + ig) * NA + 2 * jh) * DF;
    float4 E[8];
    #pragma unroll
    for (int s = 0; s < 8; ++s) E[s] = ((const float4*)de)[s];
    const float4 F0 = ((const float4*)dn)[0];
    const float4 F1 = ((const float4*)dn)[1];

    // =================== interaction 0 (no LDS, no barrier) ===================
    float zr0[KD];
    {
        float vB1s[6], vB2h[KD], msel[KD];
        #pragma unroll
        for (int a = 0; a < 6; ++a) vB1s[a] = ws[WS_B1S0 + a];
        #pragma unroll
        for (int k = 0; k < KD; ++k) vB2h[k] = ws[WS_B2H0 + k];
        #pragma unroll
        for (int k = 0; k < KD; ++k) msel[k] = same ? ws[WS_MS0 + k] : ws[WS_MA0 + k];

        // factored electron part: z = msel * (S @ W2 + cnt*B2h)
        const int scnt = ig - 8 * jh;               // self s-index if in this group
        const float fcnt = (jh == (ig >> 3)) ? 7.0f : 8.0f;
        float S[6] = {0.f, 0.f, 0.f, 0.f, 0.f, 0.f};
        #pragma unroll
        for (int s = 0; s < 8; ++s) {
            float r[6];
            wnet_r(E[s], vB1s, ws + WS_W1S0, r);
            const float mf = (s == scnt) ? 0.0f : 1.0f;
            #pragma unroll
            for (int a = 0; a < 6; ++a) S[a] = fmaf(r[a], mf, S[a]);
        }
        float z[KD];
        #pragma unroll
        for (int k = 0; k < KD; ++k) {
            float acc = fmaf(S[0], w2[k], fcnt * vB2h[k]);
            #pragma unroll
            for (int a = 1; a < 6; ++a) acc = fmaf(S[a], w2[a * KD + k], acc);
            z[k] = acc * msel[k];
        }
        // nuclear part
        {
            const float4 Ya0 = ((const float4*)Y)[4 * jh + 0];
            const float4 Ya1 = ((const float4*)Y)[4 * jh + 1];
            const float4 Yb0 = ((const float4*)Y)[4 * jh + 2];
            const float4 Yb1 = ((const float4*)Y)[4 * jh + 3];
            float r[6], racc[KD];
            wnet_r(F0, vB1s, ws + WS_W1S0, r);
            proj(r, w2, vB2h, racc);
            z[0] = fmaf(racc[0], Ya0.x, z[0]); z[1] = fmaf(racc[1], Ya0.y, z[1]);
            z[2] = fmaf(racc[2], Ya0.z, z[2]); z[3] = fmaf(racc[3], Ya0.w, z[3]);
            z[4] = fmaf(racc[4], Ya1.x, z[4]); z[5] = fmaf(racc[5], Ya1.y, z[5]);
            z[6] = fmaf(racc[6], Ya1.z, z[6]); z[7] = fmaf(racc[7], Ya1.w, z[7]);
            wnet_r(F1, vB1s, ws + WS_W1S0, r);
            proj(r, w2, vB2h, racc);
            z[0] = fmaf(racc[0], Yb0.x, z[0]); z[1] = fmaf(racc[1], Yb0.y, z[1]);
            z[2] = fmaf(racc[2], Yb0.z, z[2]); z[3] = fmaf(racc[3], Yb0.w, z[3]);
            z[4] = fmaf(racc[4], Yb1.x, z[4]); z[5] = fmaf(racc[5], Yb1.y, z[5]);
            z[6] = fmaf(racc[6], Yb1.z, z[6]); z[7] = fmaf(racc[7], Yb1.w, z[7]);
        }
        #pragma unroll
        for (int k = 0; k < KD; ++k) {
            z[k] += __shfl_xor(z[k], 16, 64);
            z[k] += __shfl_xor(z[k], 32, 64);
            zr0[k] = z[k];
        }
    }

    // =================== interaction 1 ===================
    // phase-1 via linearization: ms = Cs + zr0 @ Ms ; ma = Ca + zr0 @ Ma
    {
        float ms[KD], ma[KD];
        #pragma unroll
        for (int k = 0; k < KD; ++k) {
            float as = zr0[0] * ws[WS_MS + k];
            float aa = zr0[0] * ws[WS_MA + k];
            #pragma unroll
            for (int kp = 1; kp < KD; ++kp) {
                as = fmaf(zr0[kp], ws[WS_MS + kp * KD + k], as);
                aa = fmaf(zr0[kp], ws[WS_MA + kp * KD + k], aa);
            }
            ms[k] = as + ws[WS_CS + k];
            ma[k] = aa + ws[WS_CA + k];
        }
        if (jh == 0) {
            #pragma unroll
            for (int k = 0; k < KD; ++k) msg[el][ig][k] = ms[k];
        } else if (jh == 2) {
            #pragma unroll
            for (int k = 0; k < KD; ++k) msg[el][32 + ig][k] = ma[k];
        }
        __syncthreads();
    }

    float zr1[KD];
    {
        float vB1s[6], vB2h[KD];
        #pragma unroll
        for (int a = 0; a < 6; ++a) vB1s[a] = ws[WS_B1S1 + a];
        #pragma unroll
        for (int k = 0; k < KD; ++k) vB2h[k] = ws[WS_B2H1 + k];

        float z[KD];
        #pragma unroll
        for (int k = 0; k < KD; ++k) z[k] = 0.0f;
        #pragma unroll
        for (int s = 0; s < 8; ++s) {
            float r[6], racc[KD];
            wnet_r(E[s], vB1s, ws + WS_W1S1, r);
            proj(r, w2 + 48, vB2h, racc);
            const int j = 8 * jh + s;
            const int row = (j == ig) ? 64 : (t32 + j);
            const float4 m0 = *(const float4*)&msg[el][row][0];
            const float4 m1 = *(const float4*)&msg[el][row][4];
            z[0] = fmaf(racc[0], m0.x, z[0]); z[1] = fmaf(racc[1], m0.y, z[1]);
            z[2] = fmaf(racc[2], m0.z, z[2]); z[3] = fmaf(racc[3], m0.w, z[3]);
            z[4] = fmaf(racc[4], m1.x, z[4]); z[5] = fmaf(racc[5], m1.y, z[5]);
            z[6] = fmaf(racc[6], m1.z, z[6]); z[7] = fmaf(racc[7], m1.w, z[7]);
        }
        {
            const float4 Ya0 = ((const float4*)Y)[4 * jh + 0];
            const float4 Ya1 = ((const float4*)Y)[4 * jh + 1];
            const float4 Yb0 = ((const float4*)Y)[4 * jh + 2];
            const float4 Yb1 = ((const float4*)Y)[4 * jh + 3];
            float r[6], racc[KD];
            wnet_r(F0, vB1s, ws + WS_W1S1, r);
            proj(r, w2 + 48, vB2h, racc);
            z[0] = fmaf(racc[0], Ya0.x, z[0]); z[1] = fmaf(racc[1], Ya0.y, z[1]);
            z[2] = fmaf(racc[2], Ya0.z, z[2]); z[3] = fmaf(racc[3], Ya0.w, z[3]);
            z[4] = fmaf(racc[4], Ya1.x, z[4]); z[5] = fmaf(racc[5], Ya1.y, z[5]);
            z[6] = fmaf(racc[6], Ya1.z, z[6]); z[7] = fmaf(racc[7], Ya1.w, z[7]);
            wnet_r(F1, vB1s, ws + WS_W1S1, r);
            proj(r, w2 + 48, vB2h, racc);
            z[0] = fmaf(racc[0], Yb0.x, z[0]); z[1] = fmaf(racc[1], Yb0.y, z[1]);
            z[2] = fmaf(racc[2], Yb0.z, z[2]); z[3] = fmaf(racc[3], Yb0.w, z[3]);
            z[4] = fmaf(racc[4], Yb1.x, z[4]); z[5] = fmaf(racc[5], Yb1.y, z[5]);
            z[6] = fmaf(racc[6], Yb1.z, z[6]); z[7] = fmaf(racc[7], Yb1.w, z[7]);
        }
        #pragma unroll
        for (int k = 0; k < KD; ++k) {
            z[k] += __shfl_xor(z[k], 16, 64);
            z[k] += __shfl_xor(z[k], 32, 64);
            zr1[k] = z[k];
        }
    }

    // =================== epilogue ===================
    float dot = 0.0f;
    #pragma unroll
    for (int k = 0; k < KD; ++k) dot = fmaf(zr0[k], ws[WS_GO0 + k], dot);
    #pragma unroll
    for (int k = 0; k < KD; ++k) dot = fmaf(zr1[k], ws[WS_GO1 + k], dot);
    dot += ws[WS_BASE];
    dot *= 0.25f;    // each electron replicated across 4 lanes
    #pragma unroll
    for (int off = 1; off < 64; off <<= 1) dot += __shfl_xor(dot, off, 64);
    if (lane == 0) part[el][h] = dot;
    __syncthreads();
    if ((tid & 127) == 0) out[b] = part[el][0] + part[el][1];
}

extern "C" void kernel_launch(void* const* d_in, const int* in_sizes, int n_in,
                              void* d_out, int out_size, void* d_ws, size_t ws_size,
                              hipStream_t stream) {
    const float* dists_nuc  = (const float*)d_in[0];
    const float* dists_elec = (const float*)d_in[1];
    const float* X     = (const float*)d_in[2];
    const float* Y     = (const float*)d_in[3];
    const float* w1    = (const float*)d_in[4];
    const float* wb1   = (const float*)d_in[5];
    const float* w2    = (const float*)d_in[6];
    const float* wb2   = (const float*)d_in[7];
    const float* hs_w  = (const float*)d_in[8];
    const float* hs_b  = (const float*)d_in[9];
    const float* ha_w  = (const float*)d_in[10];
    const float* ha_b  = (const float*)d_in[11];
    const float* g_w   = (const float*)d_in[12];
    const float* g_b   = (const float*)d_in[13];
    const float* orb_w = (const float*)d_in[14];
    float* out = (float*)d_out;
    float* ws  = (float*)d_ws;

    omni_setup<<<1, 256, 0, stream>>>(X, w1, wb1, w2, wb2, hs_w, hs_b,
                                      ha_w, ha_b, g_w, g_b, orb_w, ws);
    omni_main<<<BATCH / 2, 256, 0, stream>>>(dists_nuc, dists_elec, Y, w2, ws, out);
}

// Round 6
// 157.449 us; speedup vs baseline: 1.0389x; 1.0389x over previous
//
#include <hip/hip_runtime.h>

#define NE 32   // electrons
#define NA 8    // atoms
#define DF 4    // dist features
#define KD 8    // kernel dim
#define ED 16   // embedding dim
#define BATCH 4096

// d_ws layout (floats) — all offsets even (f32x2-aligned)
#define WS_W1S0 0     // w1[n=0]*log2e   (d*6+a), 24
#define WS_W1S1 24
#define WS_B1S0 48    // wb1*log2e, 6 each
#define WS_B1S1 54
#define WS_B2H0 60    // wb2*log2e - sum_a w2[a][k], 8 each
#define WS_B2H1 68
#define WS_MS0  76    // n=0 same-spin msg vector, 8
#define WS_MA0  84    // n=0 anti-spin msg vector, 8
#define WS_MS   92    // Ms[kp][k] = (ln2*g_w0) @ hs_w1, 8x8
#define WS_MA   156   // Ma[kp][k] = (ln2*g_w0) @ ha_w1, 8x8
#define WS_CS   220   // (X+g_b0)@hs_w1 + hs_b1, 8
#define WS_CA   228
#define WS_GO0  236   // ln2*g_w0 @ orb, 8
#define WS_GO1  244
#define WS_BASE 252   // (X+g_b0+g_b1)@orb, 1

typedef float f32x2 __attribute__((ext_vector_type(2)));
__device__ __forceinline__ f32x2 splat2(float s) { f32x2 r; r.x = s; r.y = s; return r; }
__device__ __forceinline__ f32x2 fma2(f32x2 a, f32x2 b, f32x2 c) {
    return __builtin_elementwise_fma(a, b, c);
}

__global__ void omni_setup(const float* __restrict__ X,   const float* __restrict__ w1,
                           const float* __restrict__ wb1, const float* __restrict__ w2,
                           const float* __restrict__ wb2, const float* __restrict__ hs_w,
                           const float* __restrict__ hs_b,const float* __restrict__ ha_w,
                           const float* __restrict__ ha_b,const float* __restrict__ g_w,
                           const float* __restrict__ g_b, const float* __restrict__ orb_w,
                           float* __restrict__ ws)
{
    const int t = threadIdx.x;
    const float L   = 1.4426950408889634f;   // log2(e)
    const float LN2 = 0.6931471805599453f;
    if (t < 48) {                                   // W1s, both n
        ws[t] = w1[t] * L;
    } else if (t < 60) {                            // B1s
        ws[t] = wb1[t - 48] * L;
    } else if (t < 76) {                            // B2h
        const int u = t - 60, n = u >> 3, k = u & 7;
        float sw = 0.f;
        for (int a = 0; a < 6; ++a) sw += w2[n * 48 + a * KD + k];
        ws[t] = wb2[n * KD + k] * L - sw;
    } else if (t < 92) {                            // ms0 / ma0
        const int u = t - 76, tab = u >> 3, k = u & 7;
        const float* mw = tab ? ha_w : hs_w;        // n=0 slice
        const float* mb = tab ? ha_b : hs_b;
        float acc = mb[k];
        for (int c = 0; c < ED; ++c) acc += X[c] * mw[c * KD + k];
        ws[t] = acc;
    } else if (t < 220) {                           // Ms / Ma (8x8)
        int u = t - 92; const int tab = u >> 6; u &= 63;
        const int kp = u >> 3, k = u & 7;
        const float* mw = (tab ? ha_w : hs_w) + ED * KD;   // n=1 slice
        float acc = 0.f;
        for (int c = 0; c < ED; ++c)
            acc += LN2 * g_w[kp * ED + c] * mw[c * KD + k]; // g_w n=0 slice
        ws[t] = acc;
    } else if (t < 236) {                           // Cs / Ca
        const int u = t - 220, tab = u >> 3, k = u & 7;
        const float* mw = (tab ? ha_w : hs_w) + ED * KD;
        const float* mb = (tab ? ha_b : hs_b) + KD;
        float acc = mb[k];
        for (int c = 0; c < ED; ++c) acc += (X[c] + g_b[c]) * mw[c * KD + k];
        ws[t] = acc;
    } else if (t < 252) {                           // go0 / go1
        const int u = t - 236, n = u >> 3, k = u & 7;
        float acc = 0.f;
        for (int c = 0; c < ED; ++c)
            acc += LN2 * g_w[n * KD * ED + k * ED + c] * orb_w[c];
        ws[t] = acc;
    } else if (t == 252) {                          // base
        float acc = 0.f;
        for (int c = 0; c < ED; ++c) acc += (X[c] + g_b[c] + g_b[ED + c]) * orb_w[c];
        ws[t] = acc;
    }
}

// trans stage, k-packed: r2[a2] = log2(1 + 2^(e@W1s + B1s)) for unit pair a2
__device__ __forceinline__ void wnet_r2(const float4 e,
                                        const f32x2* __restrict__ vB1s2,  // 3
                                        const f32x2* __restrict__ sW12,   // 12: d*3+a2
                                        f32x2* __restrict__ r2)           // 3
{
    #pragma unroll
    for (int a2 = 0; a2 < 3; ++a2) {
        f32x2 u = fma2(splat2(e.x), sW12[a2], vB1s2[a2]);
        u = fma2(splat2(e.y), sW12[3 + a2], u);
        u = fma2(splat2(e.z), sW12[6 + a2], u);
        u = fma2(splat2(e.w), sW12[9 + a2], u);
        f32x2 t;
        t.x = __builtin_amdgcn_exp2f(u.x);
        t.y = __builtin_amdgcn_exp2f(u.y);
        t = t + splat2(1.0f);
        r2[a2].x = __builtin_amdgcn_logf(t.x);
        r2[a2].y = __builtin_amdgcn_logf(t.y);
    }
}

// projection, k-packed: racc2[k2] = B2h2[k2] + sum_a r[a]*W2[a][k-pair]
__device__ __forceinline__ void proj2(const f32x2* __restrict__ r2,
                                      const f32x2* __restrict__ sW22,   // 24: a*4+k2
                                      const f32x2* __restrict__ vB2h2,  // 4
                                      f32x2* __restrict__ racc2)        // 4
{
    #pragma unroll
    for (int k2 = 0; k2 < 4; ++k2) {
        f32x2 acc = vB2h2[k2];
        acc = fma2(splat2(r2[0].x), sW22[0 * 4 + k2], acc);
        acc = fma2(splat2(r2[0].y), sW22[1 * 4 + k2], acc);
        acc = fma2(splat2(r2[1].x), sW22[2 * 4 + k2], acc);
        acc = fma2(splat2(r2[1].y), sW22[3 * 4 + k2], acc);
        acc = fma2(splat2(r2[2].x), sW22[4 * 4 + k2], acc);
        acc = fma2(splat2(r2[2].y), sW22[5 * 4 + k2], acc);
        racc2[k2] = acc;
    }
}

__global__ __launch_bounds__(128, 4) void omni_main(
    const float* __restrict__ dists_nuc,   // (B, NE, NA, DF)
    const float* __restrict__ dists_elec,  // (B, NE, NE, DF)
    const float* __restrict__ Y,           // (NA, KD)
    const float* __restrict__ w2,          // (2, 6, KD)
    const float* __restrict__ ws,          // precomputed constants
    float* __restrict__ out)               // (B,)
{
    const int tid  = threadIdx.x;
    const int h    = tid >> 6;          // wave: electrons of spin h
    const int lane = tid & 63;
    const int il   = lane & 15;
    const int jh   = lane >> 4;         // j quarter (j in [8jh, 8jh+8))
    const int ig   = 16 * h + il;       // this lane's electron
    const int b    = blockIdx.x;
    const int sj   = jh >> 1;           // spin of j range
    const bool same = (sj == h);
    const int t32  = same ? 0 : 32;

    __shared__ float msg[65][KD];       // n=1 table; row 64 = zeros
    __shared__ float part[2];
    if (tid < KD) msg[64][tid] = 0.0f;

    const f32x2* ws2  = (const f32x2*)ws;
    const f32x2* w2p0 = (const f32x2*)w2;          // n=0: a*4+k2
    const f32x2* w2p1 = (const f32x2*)(w2 + 48);   // n=1

    // ---- register-cache distances & Y rows (reused by both interactions) ----
    const float* de = dists_elec + (((size_t)b * NE + ig) * NE + 8 * jh) * DF;
    const float* dn = dists_nuc  + (((size_t)b * NE + ig) * NA + 2 * jh) * DF;
    float4 E[8];
    #pragma unroll
    for (int s = 0; s < 8; ++s) E[s] = ((const float4*)de)[s];
    const float4 F0 = ((const float4*)dn)[0];
    const float4 F1 = ((const float4*)dn)[1];
    f32x2 Y0[4], Y1[4];
    #pragma unroll
    for (int k2 = 0; k2 < 4; ++k2) {
        Y0[k2] = ((const f32x2*)Y)[(2 * jh) * 4 + k2];
        Y1[k2] = ((const f32x2*)Y)[(2 * jh + 1) * 4 + k2];
    }

    // =================== interaction 0 (no LDS, no barrier) ===================
    float zr0[KD];
    {
        f32x2 vB1s2[3], vB2h2[4], msel2[4];
        #pragma unroll
        for (int a2 = 0; a2 < 3; ++a2) vB1s2[a2] = ws2[WS_B1S0 / 2 + a2];
        #pragma unroll
        for (int k2 = 0; k2 < 4; ++k2) vB2h2[k2] = ws2[WS_B2H0 / 2 + k2];
        #pragma unroll
        for (int k2 = 0; k2 < 4; ++k2)
            msel2[k2] = same ? ws2[WS_MS0 / 2 + k2] : ws2[WS_MA0 / 2 + k2];

        // factored electron part: z = msel * (S @ W2 + cnt*B2h)
        const int scnt  = ig - 8 * jh;
        const float fcnt = (jh == (ig >> 3)) ? 7.0f : 8.0f;
        f32x2 S2[3] = {splat2(0.f), splat2(0.f), splat2(0.f)};
        #pragma unroll
        for (int s = 0; s < 8; ++s) {
            f32x2 r2[3];
            wnet_r2(E[s], vB1s2, ws2 + WS_W1S0 / 2, r2);
            const float mf = (s == scnt) ? 0.0f : 1.0f;
            #pragma unroll
            for (int a2 = 0; a2 < 3; ++a2) S2[a2] = fma2(r2[a2], splat2(mf), S2[a2]);
        }
        f32x2 z2[4];
        #pragma unroll
        for (int k2 = 0; k2 < 4; ++k2) {
            f32x2 acc = splat2(fcnt) * vB2h2[k2];
            acc = fma2(splat2(S2[0].x), w2p0[0 * 4 + k2], acc);
            acc = fma2(splat2(S2[0].y), w2p0[1 * 4 + k2], acc);
            acc = fma2(splat2(S2[1].x), w2p0[2 * 4 + k2], acc);
            acc = fma2(splat2(S2[1].y), w2p0[3 * 4 + k2], acc);
            acc = fma2(splat2(S2[2].x), w2p0[4 * 4 + k2], acc);
            acc = fma2(splat2(S2[2].y), w2p0[5 * 4 + k2], acc);
            z2[k2] = acc * msel2[k2];
        }
        // nuclear part
        {
            f32x2 r2[3], racc2[4];
            wnet_r2(F0, vB1s2, ws2 + WS_W1S0 / 2, r2);
            proj2(r2, w2p0, vB2h2, racc2);
            #pragma unroll
            for (int k2 = 0; k2 < 4; ++k2) z2[k2] = fma2(racc2[k2], Y0[k2], z2[k2]);
            wnet_r2(F1, vB1s2, ws2 + WS_W1S0 / 2, r2);
            proj2(r2, w2p0, vB2h2, racc2);
            #pragma unroll
            for (int k2 = 0; k2 < 4; ++k2) z2[k2] = fma2(racc2[k2], Y1[k2], z2[k2]);
        }
        #pragma unroll
        for (int k2 = 0; k2 < 4; ++k2) {
            float za = z2[k2].x, zb = z2[k2].y;
            za += __shfl_xor(za, 16, 64); za += __shfl_xor(za, 32, 64);
            zb += __shfl_xor(zb, 16, 64); zb += __shfl_xor(zb, 32, 64);
            zr0[2 * k2] = za; zr0[2 * k2 + 1] = zb;
        }
    }

    // =================== interaction 1 ===================
    // phase-1 via linearization: ms = Cs + zr0 @ Ms ; ma = Ca + zr0 @ Ma
    {
        f32x2 ms2[4], ma2[4];
        #pragma unroll
        for (int k2 = 0; k2 < 4; ++k2) {
            ms2[k2] = ws2[WS_CS / 2 + k2];
            ma2[k2] = ws2[WS_CA / 2 + k2];
        }
        #pragma unroll
        for (int kp = 0; kp < KD; ++kp) {
            const f32x2 zk = splat2(zr0[kp]);
            #pragma unroll
            for (int k2 = 0; k2 < 4; ++k2) {
                ms2[k2] = fma2(zk, ws2[WS_MS / 2 + kp * 4 + k2], ms2[k2]);
                ma2[k2] = fma2(zk, ws2[WS_MA / 2 + kp * 4 + k2], ma2[k2]);
            }
        }
        if (jh == 0) {
            #pragma unroll
            for (int k2 = 0; k2 < 4; ++k2) *(f32x2*)&msg[ig][2 * k2] = ms2[k2];
        } else if (jh == 2) {
            #pragma unroll
            for (int k2 = 0; k2 < 4; ++k2) *(f32x2*)&msg[32 + ig][2 * k2] = ma2[k2];
        }
        __syncthreads();
    }

    float zr1[KD];
    {
        f32x2 vB1s2[3], vB2h2[4];
        #pragma unroll
        for (int a2 = 0; a2 < 3; ++a2) vB1s2[a2] = ws2[WS_B1S1 / 2 + a2];
        #pragma unroll
        for (int k2 = 0; k2 < 4; ++k2) vB2h2[k2] = ws2[WS_B2H1 / 2 + k2];

        f32x2 z2[4] = {splat2(0.f), splat2(0.f), splat2(0.f), splat2(0.f)};
        #pragma unroll
        for (int s = 0; s < 8; ++s) {
            f32x2 r2[3], racc2[4];
            wnet_r2(E[s], vB1s2, ws2 + WS_W1S1 / 2, r2);
            proj2(r2, w2p1, vB2h2, racc2);
            const int j = 8 * jh + s;
            const int row = (j == ig) ? 64 : (t32 + j);
            const f32x2* mrow = (const f32x2*)&msg[row][0];
            #pragma unroll
            for (int k2 = 0; k2 < 4; ++k2) z2[k2] = fma2(racc2[k2], mrow[k2], z2[k2]);
        }
        {
            f32x2 r2[3], racc2[4];
            wnet_r2(F0, vB1s2, ws2 + WS_W1S1 / 2, r2);
            proj2(r2, w2p1, vB2h2, racc2);
            #pragma unroll
            for (int k2 = 0; k2 < 4; ++k2) z2[k2] = fma2(racc2[k2], Y0[k2], z2[k2]);
            wnet_r2(F1, vB1s2, ws2 + WS_W1S1 / 2, r2);
            proj2(r2, w2p1, vB2h2, racc2);
            #pragma unroll
            for (int k2 = 0; k2 < 4; ++k2) z2[k2] = fma2(racc2[k2], Y1[k2], z2[k2]);
        }
        #pragma unroll
        for (int k2 = 0; k2 < 4; ++k2) {
            float za = z2[k2].x, zb = z2[k2].y;
            za += __shfl_xor(za, 16, 64); za += __shfl_xor(za, 32, 64);
            zb += __shfl_xor(zb, 16, 64); zb += __shfl_xor(zb, 32, 64);
            zr1[2 * k2] = za; zr1[2 * k2 + 1] = zb;
        }
    }

    // =================== epilogue ===================
    float dot = 0.0f;
    #pragma unroll
    for (int k = 0; k < KD; ++k) dot = fmaf(zr0[k], ws[WS_GO0 + k], dot);
    #pragma unroll
    for (int k = 0; k < KD; ++k) dot = fmaf(zr1[k], ws[WS_GO1 + k], dot);
    dot += ws[WS_BASE];
    dot *= 0.25f;    // each electron replicated across 4 lanes
    #pragma unroll
    for (int off = 1; off < 64; off <<= 1) dot += __shfl_xor(dot, off, 64);
    if (lane == 0) part[h] = dot;
    __syncthreads();
    if (tid == 0) out[b] = part[0] + part[1];
}

extern "C" void kernel_launch(void* const* d_in, const int* in_sizes, int n_in,
                              void* d_out, int out_size, void* d_ws, size_t ws_size,
                              hipStream_t stream) {
    const float* dists_nuc  = (const float*)d_in[0];
    const float* dists_elec = (const float*)d_in[1];
    const float* X     = (const float*)d_in[2];
    const float* Y     = (const float*)d_in[3];
    const float* w1    = (const float*)d_in[4];
    const float* wb1   = (const float*)d_in[5];
    const float* w2    = (const float*)d_in[6];
    const float* wb2   = (const float*)d_in[7];
    const float* hs_w  = (const float*)d_in[8];
    const float* hs_b  = (const float*)d_in[9];
    const float* ha_w  = (const float*)d_in[10];
    const float* ha_b  = (const float*)d_in[11];
    const float* g_w   = (const float*)d_in[12];
    const float* g_b   = (const float*)d_in[13];
    const float* orb_w = (const float*)d_in[14];
    float* out = (float*)d_out;
    float* ws  = (float*)d_ws;

    omni_setup<<<1, 256, 0, stream>>>(X, w1, wb1, w2, wb2, hs_w, hs_b,
                                      ha_w, ha_b, g_w, g_b, orb_w, ws);
    omni_main<<<BATCH, 128, 0, stream>>>(dists_nuc, dists_elec, Y, w2, ws, out);
}

// Round 7
// 156.420 us; speedup vs baseline: 1.0458x; 1.0066x over previous
//
#include <hip/hip_runtime.h>

#define NE 32   // electrons
#define NA 8    // atoms
#define DF 4    // dist features
#define KD 8    // kernel dim
#define ED 16   // embedding dim
#define BATCH 4096

// d_ws layout (floats) — all offsets even (f32x2-aligned)
#define WS_W1S0 0     // w1[n=0]*log2e   (d*6+a), 24
#define WS_W1S1 24
#define WS_B1S0 48    // wb1*log2e, 6 each
#define WS_B1S1 54
#define WS_B2H0 60    // wb2*log2e - sum_a w2[a][k], 8 each
#define WS_B2H1 68
#define WS_MS0  76    // n=0 same-spin msg vector, 8
#define WS_MA0  84    // n=0 anti-spin msg vector, 8
#define WS_MS   92    // Ms[kp][k] = (ln2*g_w0) @ hs_w1, 8x8
#define WS_MA   156   // Ma[kp][k] = (ln2*g_w0) @ ha_w1, 8x8
#define WS_CS   220   // (X+g_b0)@hs_w1 + hs_b1, 8
#define WS_CA   228
#define WS_GO0  236   // ln2*g_w0 @ orb, 8
#define WS_GO1  244
#define WS_BASE 252   // (X+g_b0+g_b1)@orb, 1

typedef float f32x2 __attribute__((ext_vector_type(2)));
__device__ __forceinline__ f32x2 splat2(float s) { f32x2 r; r.x = s; r.y = s; return r; }
__device__ __forceinline__ f32x2 fma2(f32x2 a, f32x2 b, f32x2 c) {
    return __builtin_elementwise_fma(a, b, c);
}

__global__ void omni_setup(const float* __restrict__ X,   const float* __restrict__ w1,
                           const float* __restrict__ wb1, const float* __restrict__ w2,
                           const float* __restrict__ wb2, const float* __restrict__ hs_w,
                           const float* __restrict__ hs_b,const float* __restrict__ ha_w,
                           const float* __restrict__ ha_b,const float* __restrict__ g_w,
                           const float* __restrict__ g_b, const float* __restrict__ orb_w,
                           float* __restrict__ ws)
{
    const int t = threadIdx.x;
    const float L   = 1.4426950408889634f;   // log2(e)
    const float LN2 = 0.6931471805599453f;
    if (t < 48) {                                   // W1s, both n
        ws[t] = w1[t] * L;
    } else if (t < 60) {                            // B1s
        ws[t] = wb1[t - 48] * L;
    } else if (t < 76) {                            // B2h
        const int u = t - 60, n = u >> 3, k = u & 7;
        float sw = 0.f;
        for (int a = 0; a < 6; ++a) sw += w2[n * 48 + a * KD + k];
        ws[t] = wb2[n * KD + k] * L - sw;
    } else if (t < 92) {                            // ms0 / ma0
        const int u = t - 76, tab = u >> 3, k = u & 7;
        const float* mw = tab ? ha_w : hs_w;        // n=0 slice
        const float* mb = tab ? ha_b : hs_b;
        float acc = mb[k];
        for (int c = 0; c < ED; ++c) acc += X[c] * mw[c * KD + k];
        ws[t] = acc;
    } else if (t < 220) {                           // Ms / Ma (8x8)
        int u = t - 92; const int tab = u >> 6; u &= 63;
        const int kp = u >> 3, k = u & 7;
        const float* mw = (tab ? ha_w : hs_w) + ED * KD;   // n=1 slice
        float acc = 0.f;
        for (int c = 0; c < ED; ++c)
            acc += LN2 * g_w[kp * ED + c] * mw[c * KD + k]; // g_w n=0 slice
        ws[t] = acc;
    } else if (t < 236) {                           // Cs / Ca
        const int u = t - 220, tab = u >> 3, k = u & 7;
        const float* mw = (tab ? ha_w : hs_w) + ED * KD;
        const float* mb = (tab ? ha_b : hs_b) + KD;
        float acc = mb[k];
        for (int c = 0; c < ED; ++c) acc += (X[c] + g_b[c]) * mw[c * KD + k];
        ws[t] = acc;
    } else if (t < 252) {                           // go0 / go1
        const int u = t - 236, n = u >> 3, k = u & 7;
        float acc = 0.f;
        for (int c = 0; c < ED; ++c)
            acc += LN2 * g_w[n * KD * ED + k * ED + c] * orb_w[c];
        ws[t] = acc;
    } else if (t == 252) {                          // base
        float acc = 0.f;
        for (int c = 0; c < ED; ++c) acc += (X[c] + g_b[c] + g_b[ED + c]) * orb_w[c];
        ws[t] = acc;
    }
}

// trans stage, k-packed: r2[a2] = log2(1 + 2^(e@W1s + B1s)) for unit pair a2
__device__ __forceinline__ void wnet_r2(const float4 e,
                                        const f32x2* __restrict__ vB1s2,  // 3
                                        const f32x2* __restrict__ sW12,   // 12: d*3+a2
                                        f32x2* __restrict__ r2)           // 3
{
    #pragma unroll
    for (int a2 = 0; a2 < 3; ++a2) {
        f32x2 u = fma2(splat2(e.x), sW12[a2], vB1s2[a2]);
        u = fma2(splat2(e.y), sW12[3 + a2], u);
        u = fma2(splat2(e.z), sW12[6 + a2], u);
        u = fma2(splat2(e.w), sW12[9 + a2], u);
        f32x2 t;
        t.x = __builtin_amdgcn_exp2f(u.x);
        t.y = __builtin_amdgcn_exp2f(u.y);
        t = t + splat2(1.0f);
        r2[a2].x = __builtin_amdgcn_logf(t.x);
        r2[a2].y = __builtin_amdgcn_logf(t.y);
    }
}

// projection, k-packed: racc2[k2] = B2h2[k2] + sum_a r[a]*W2[a][k-pair]
__device__ __forceinline__ void proj2(const f32x2* __restrict__ r2,
                                      const f32x2* __restrict__ sW22,   // 24: a*4+k2
                                      const f32x2* __restrict__ vB2h2,  // 4
                                      f32x2* __restrict__ racc2)        // 4
{
    #pragma unroll
    for (int k2 = 0; k2 < 4; ++k2) {
        f32x2 acc = vB2h2[k2];
        acc = fma2(splat2(r2[0].x), sW22[0 * 4 + k2], acc);
        acc = fma2(splat2(r2[0].y), sW22[1 * 4 + k2], acc);
        acc = fma2(splat2(r2[1].x), sW22[2 * 4 + k2], acc);
        acc = fma2(splat2(r2[1].y), sW22[3 * 4 + k2], acc);
        acc = fma2(splat2(r2[2].x), sW22[4 * 4 + k2], acc);
        acc = fma2(splat2(r2[2].y), sW22[5 * 4 + k2], acc);
        racc2[k2] = acc;
    }
}

__global__ __launch_bounds__(128) void omni_main(
    const float* __restrict__ dists_nuc,   // (B, NE, NA, DF)
    const float* __restrict__ dists_elec,  // (B, NE, NE, DF)
    const float* __restrict__ Y,           // (NA, KD)
    const float* __restrict__ w2,          // (2, 6, KD)
    const float* __restrict__ ws,          // precomputed constants
    float* __restrict__ out)               // (B,)
{
    const int tid  = threadIdx.x;
    const int h    = tid >> 6;          // wave: electrons of spin h
    const int lane = tid & 63;
    const int il   = lane & 15;
    const int jh   = lane >> 4;         // j quarter (j in [8jh, 8jh+8))
    const int ig   = 16 * h + il;       // this lane's electron
    const int b    = blockIdx.x;
    const int sj   = jh >> 1;           // spin of j range
    const bool same = (sj == h);
    const int t32  = same ? 0 : 32;

    __shared__ float msg[65][KD];       // n=1 table; row 64 = zeros
    __shared__ float part[2];
    if (tid < KD) msg[64][tid] = 0.0f;

    const f32x2* ws2  = (const f32x2*)ws;
    const f32x2* w2p0 = (const f32x2*)w2;          // n=0: a*4+k2
    const f32x2* w2p1 = (const f32x2*)(w2 + 48);   // n=1
    const f32x2* Yp   = (const f32x2*)Y;

    // NO persistent register caches — loads are issued at each use site
    // (the n=1 re-reads hit L1/L2; keeping them live caused 49 MB of spills in R5).
    const float* de = dists_elec + (((size_t)b * NE + ig) * NE + 8 * jh) * DF;
    const float* dn = dists_nuc  + (((size_t)b * NE + ig) * NA + 2 * jh) * DF;

    // =================== interaction 0 (no LDS, no barrier) ===================
    float zr0[KD];
    {
        f32x2 vB1s2[3], vB2h2[4], msel2[4];
        #pragma unroll
        for (int a2 = 0; a2 < 3; ++a2) vB1s2[a2] = ws2[WS_B1S0 / 2 + a2];
        #pragma unroll
        for (int k2 = 0; k2 < 4; ++k2) vB2h2[k2] = ws2[WS_B2H0 / 2 + k2];
        #pragma unroll
        for (int k2 = 0; k2 < 4; ++k2)
            msel2[k2] = same ? ws2[WS_MS0 / 2 + k2] : ws2[WS_MA0 / 2 + k2];

        // factored electron part: z = msel * (S @ W2 + cnt*B2h)
        const int scnt  = ig - 8 * jh;
        const float fcnt = (jh == (ig >> 3)) ? 7.0f : 8.0f;
        f32x2 S2[3] = {splat2(0.f), splat2(0.f), splat2(0.f)};
        #pragma unroll
        for (int s = 0; s < 8; ++s) {
            const float4 e = ((const float4*)de)[s];
            f32x2 r2[3];
            wnet_r2(e, vB1s2, ws2 + WS_W1S0 / 2, r2);
            const float mf = (s == scnt) ? 0.0f : 1.0f;
            #pragma unroll
            for (int a2 = 0; a2 < 3; ++a2) S2[a2] = fma2(r2[a2], splat2(mf), S2[a2]);
        }
        f32x2 z2[4];
        #pragma unroll
        for (int k2 = 0; k2 < 4; ++k2) {
            f32x2 acc = splat2(fcnt) * vB2h2[k2];
            acc = fma2(splat2(S2[0].x), w2p0[0 * 4 + k2], acc);
            acc = fma2(splat2(S2[0].y), w2p0[1 * 4 + k2], acc);
            acc = fma2(splat2(S2[1].x), w2p0[2 * 4 + k2], acc);
            acc = fma2(splat2(S2[1].y), w2p0[3 * 4 + k2], acc);
            acc = fma2(splat2(S2[2].x), w2p0[4 * 4 + k2], acc);
            acc = fma2(splat2(S2[2].y), w2p0[5 * 4 + k2], acc);
            z2[k2] = acc * msel2[k2];
        }
        // nuclear part
        {
            const float4 f0 = ((const float4*)dn)[0];
            const float4 f1 = ((const float4*)dn)[1];
            f32x2 r2[3], racc2[4];
            wnet_r2(f0, vB1s2, ws2 + WS_W1S0 / 2, r2);
            proj2(r2, w2p0, vB2h2, racc2);
            #pragma unroll
            for (int k2 = 0; k2 < 4; ++k2)
                z2[k2] = fma2(racc2[k2], Yp[(2 * jh) * 4 + k2], z2[k2]);
            wnet_r2(f1, vB1s2, ws2 + WS_W1S0 / 2, r2);
            proj2(r2, w2p0, vB2h2, racc2);
            #pragma unroll
            for (int k2 = 0; k2 < 4; ++k2)
                z2[k2] = fma2(racc2[k2], Yp[(2 * jh + 1) * 4 + k2], z2[k2]);
        }
        #pragma unroll
        for (int k2 = 0; k2 < 4; ++k2) {
            float za = z2[k2].x, zb = z2[k2].y;
            za += __shfl_xor(za, 16, 64); za += __shfl_xor(za, 32, 64);
            zb += __shfl_xor(zb, 16, 64); zb += __shfl_xor(zb, 32, 64);
            zr0[2 * k2] = za; zr0[2 * k2 + 1] = zb;
        }
    }

    // =================== interaction 1 ===================
    // phase-1 via linearization: ms = Cs + zr0 @ Ms ; ma = Ca + zr0 @ Ma
    {
        f32x2 ms2[4], ma2[4];
        #pragma unroll
        for (int k2 = 0; k2 < 4; ++k2) {
            ms2[k2] = ws2[WS_CS / 2 + k2];
            ma2[k2] = ws2[WS_CA / 2 + k2];
        }
        #pragma unroll
        for (int kp = 0; kp < KD; ++kp) {
            const f32x2 zk = splat2(zr0[kp]);
            #pragma unroll
            for (int k2 = 0; k2 < 4; ++k2) {
                ms2[k2] = fma2(zk, ws2[WS_MS / 2 + kp * 4 + k2], ms2[k2]);
                ma2[k2] = fma2(zk, ws2[WS_MA / 2 + kp * 4 + k2], ma2[k2]);
            }
        }
        if (jh == 0) {
            #pragma unroll
            for (int k2 = 0; k2 < 4; ++k2) *(f32x2*)&msg[ig][2 * k2] = ms2[k2];
        } else if (jh == 2) {
            #pragma unroll
            for (int k2 = 0; k2 < 4; ++k2) *(f32x2*)&msg[32 + ig][2 * k2] = ma2[k2];
        }
        __syncthreads();
    }

    float zr1[KD];
    {
        f32x2 vB1s2[3], vB2h2[4];
        #pragma unroll
        for (int a2 = 0; a2 < 3; ++a2) vB1s2[a2] = ws2[WS_B1S1 / 2 + a2];
        #pragma unroll
        for (int k2 = 0; k2 < 4; ++k2) vB2h2[k2] = ws2[WS_B2H1 / 2 + k2];

        f32x2 z2[4] = {splat2(0.f), splat2(0.f), splat2(0.f), splat2(0.f)};
        #pragma unroll
        for (int s = 0; s < 8; ++s) {
            const float4 e = ((const float4*)de)[s];   // L1/L2-resident re-read
            f32x2 r2[3], racc2[4];
            wnet_r2(e, vB1s2, ws2 + WS_W1S1 / 2, r2);
            proj2(r2, w2p1, vB2h2, racc2);
            const int j = 8 * jh + s;
            const int row = (j == ig) ? 64 : (t32 + j);
            const f32x2* mrow = (const f32x2*)&msg[row][0];
            #pragma unroll
            for (int k2 = 0; k2 < 4; ++k2) z2[k2] = fma2(racc2[k2], mrow[k2], z2[k2]);
        }
        {
            const float4 f0 = ((const float4*)dn)[0];
            const float4 f1 = ((const float4*)dn)[1];
            f32x2 r2[3], racc2[4];
            wnet_r2(f0, vB1s2, ws2 + WS_W1S1 / 2, r2);
            proj2(r2, w2p1, vB2h2, racc2);
            #pragma unroll
            for (int k2 = 0; k2 < 4; ++k2)
                z2[k2] = fma2(racc2[k2], Yp[(2 * jh) * 4 + k2], z2[k2]);
            wnet_r2(f1, vB1s2, ws2 + WS_W1S1 / 2, r2);
            proj2(r2, w2p1, vB2h2, racc2);
            #pragma unroll
            for (int k2 = 0; k2 < 4; ++k2)
                z2[k2] = fma2(racc2[k2], Yp[(2 * jh + 1) * 4 + k2], z2[k2]);
        }
        #pragma unroll
        for (int k2 = 0; k2 < 4; ++k2) {
            float za = z2[k2].x, zb = z2[k2].y;
            za += __shfl_xor(za, 16, 64); za += __shfl_xor(za, 32, 64);
            zb += __shfl_xor(zb, 16, 64); zb += __shfl_xor(zb, 32, 64);
            zr1[2 * k2] = za; zr1[2 * k2 + 1] = zb;
        }
    }

    // =================== epilogue ===================
    float dot = 0.0f;
    #pragma unroll
    for (int k = 0; k < KD; ++k) dot = fmaf(zr0[k], ws[WS_GO0 + k], dot);
    #pragma unroll
    for (int k = 0; k < KD; ++k) dot = fmaf(zr1[k], ws[WS_GO1 + k], dot);
    dot += ws[WS_BASE];
    dot *= 0.25f;    // each electron replicated across 4 lanes
    #pragma unroll
    for (int off = 1; off < 64; off <<= 1) dot += __shfl_xor(dot, off, 64);
    if (lane == 0) part[h] = dot;
    __syncthreads();
    if (tid == 0) out[b] = part[0] + part[1];
}

extern "C" void kernel_launch(void* const* d_in, const int* in_sizes, int n_in,
                              void* d_out, int out_size, void* d_ws, size_t ws_size,
                              hipStream_t stream) {
    const float* dists_nuc  = (const float*)d_in[0];
    const float* dists_elec = (const float*)d_in[1];
    const float* X     = (const float*)d_in[2];
    const float* Y     = (const float*)d_in[3];
    const float* w1    = (const float*)d_in[4];
    const float* wb1   = (const float*)d_in[5];
    const float* w2    = (const float*)d_in[6];
    const float* wb2   = (const float*)d_in[7];
    const float* hs_w  = (const float*)d_in[8];
    const float* hs_b  = (const float*)d_in[9];
    const float* ha_w  = (const float*)d_in[10];
    const float* ha_b  = (const float*)d_in[11];
    const float* g_w   = (const float*)d_in[12];
    const float* g_b   = (const float*)d_in[13];
    const float* orb_w = (const float*)d_in[14];
    float* out = (float*)d_out;
    float* ws  = (float*)d_ws;

    omni_setup<<<1, 256, 0, stream>>>(X, w1, wb1, w2, wb2, hs_w, hs_b,
                                      ha_w, ha_b, g_w, g_b, orb_w, ws);
    omni_main<<<BATCH, 128, 0, stream>>>(dists_nuc, dists_elec, Y, w2, ws, out);
}

// Round 8
// 143.888 us; speedup vs baseline: 1.1369x; 1.0871x over previous
//
#include <hip/hip_runtime.h>

#define NE 32   // electrons
#define NA 8    // atoms
#define DF 4    // dist features
#define KD 8    // kernel dim
#define ED 16   // embedding dim
#define BATCH 4096

// d_ws layout (floats) — all offsets even (f32x2-aligned)
#define WS_W1S0 0     // w1[n=0]*log2e   (d*6+a), 24
#define WS_W1S1 24
#define WS_B1S0 48    // wb1*log2e, 6 each
#define WS_B1S1 54
#define WS_B2H0 60    // wb2*log2e - sum_a w2[a][k], 8 each
#define WS_B2H1 68
#define WS_MS0  76    // n=0 same-spin msg vector, 8
#define WS_MA0  84    // n=0 anti-spin msg vector, 8
#define WS_MS   92    // Ms[kp][k] = (ln2*g_w0) @ hs_w1, 8x8
#define WS_MA   156   // Ma[kp][k] = (ln2*g_w0) @ ha_w1, 8x8
#define WS_CS   220   // (X+g_b0)@hs_w1 + hs_b1, 8
#define WS_CA   228
#define WS_GO0  236   // ln2*g_w0 @ orb, 8
#define WS_GO1  244
#define WS_BASE 252   // (X+g_b0+g_b1)@orb, 1

typedef float f32x2 __attribute__((ext_vector_type(2)));
__device__ __forceinline__ f32x2 splat2(float s) { f32x2 r; r.x = s; r.y = s; return r; }
__device__ __forceinline__ f32x2 fma2(f32x2 a, f32x2 b, f32x2 c) {
    return __builtin_elementwise_fma(a, b, c);
}

__global__ void omni_setup(const float* __restrict__ X,   const float* __restrict__ w1,
                           const float* __restrict__ wb1, const float* __restrict__ w2,
                           const float* __restrict__ wb2, const float* __restrict__ hs_w,
                           const float* __restrict__ hs_b,const float* __restrict__ ha_w,
                           const float* __restrict__ ha_b,const float* __restrict__ g_w,
                           const float* __restrict__ g_b, const float* __restrict__ orb_w,
                           float* __restrict__ ws)
{
    const int t = threadIdx.x;
    const float L   = 1.4426950408889634f;   // log2(e)
    const float LN2 = 0.6931471805599453f;
    if (t < 48) {                                   // W1s, both n
        ws[t] = w1[t] * L;
    } else if (t < 60) {                            // B1s
        ws[t] = wb1[t - 48] * L;
    } else if (t < 76) {                            // B2h
        const int u = t - 60, n = u >> 3, k = u & 7;
        float sw = 0.f;
        for (int a = 0; a < 6; ++a) sw += w2[n * 48 + a * KD + k];
        ws[t] = wb2[n * KD + k] * L - sw;
    } else if (t < 92) {                            // ms0 / ma0
        const int u = t - 76, tab = u >> 3, k = u & 7;
        const float* mw = tab ? ha_w : hs_w;        // n=0 slice
        const float* mb = tab ? ha_b : hs_b;
        float acc = mb[k];
        for (int c = 0; c < ED; ++c) acc += X[c] * mw[c * KD + k];
        ws[t] = acc;
    } else if (t < 220) {                           // Ms / Ma (8x8)
        int u = t - 92; const int tab = u >> 6; u &= 63;
        const int kp = u >> 3, k = u & 7;
        const float* mw = (tab ? ha_w : hs_w) + ED * KD;   // n=1 slice
        float acc = 0.f;
        for (int c = 0; c < ED; ++c)
            acc += LN2 * g_w[kp * ED + c] * mw[c * KD + k]; // g_w n=0 slice
        ws[t] = acc;
    } else if (t < 236) {                           // Cs / Ca
        const int u = t - 220, tab = u >> 3, k = u & 7;
        const float* mw = (tab ? ha_w : hs_w) + ED * KD;
        const float* mb = (tab ? ha_b : hs_b) + KD;
        float acc = mb[k];
        for (int c = 0; c < ED; ++c) acc += (X[c] + g_b[c]) * mw[c * KD + k];
        ws[t] = acc;
    } else if (t < 252) {                           // go0 / go1
        const int u = t - 236, n = u >> 3, k = u & 7;
        float acc = 0.f;
        for (int c = 0; c < ED; ++c)
            acc += LN2 * g_w[n * KD * ED + k * ED + c] * orb_w[c];
        ws[t] = acc;
    } else if (t == 252) {                          // base
        float acc = 0.f;
        for (int c = 0; c < ED; ++c) acc += (X[c] + g_b[c] + g_b[ED + c]) * orb_w[c];
        ws[t] = acc;
    }
}

// trans stage, k-packed: r2[a2] = log2(1 + 2^(e@W1s + B1s)) for unit pair a2
__device__ __forceinline__ void wnet_r2(const float4 e,
                                        const f32x2* __restrict__ vB1s2,  // 3
                                        const f32x2* __restrict__ sW12,   // 12: d*3+a2
                                        f32x2* __restrict__ r2)           // 3
{
    #pragma unroll
    for (int a2 = 0; a2 < 3; ++a2) {
        f32x2 u = fma2(splat2(e.x), sW12[a2], vB1s2[a2]);
        u = fma2(splat2(e.y), sW12[3 + a2], u);
        u = fma2(splat2(e.z), sW12[6 + a2], u);
        u = fma2(splat2(e.w), sW12[9 + a2], u);
        f32x2 t;
        t.x = __builtin_amdgcn_exp2f(u.x);
        t.y = __builtin_amdgcn_exp2f(u.y);
        t = t + splat2(1.0f);
        r2[a2].x = __builtin_amdgcn_logf(t.x);
        r2[a2].y = __builtin_amdgcn_logf(t.y);
    }
}

// projection, k-packed: racc2[k2] = B2h2[k2] + sum_a r[a]*W2[a][k-pair]
__device__ __forceinline__ void proj2(const f32x2* __restrict__ r2,
                                      const f32x2* __restrict__ sW22,   // 24: a*4+k2
                                      const f32x2* __restrict__ vB2h2,  // 4
                                      f32x2* __restrict__ racc2)        // 4
{
    #pragma unroll
    for (int k2 = 0; k2 < 4; ++k2) {
        f32x2 acc = vB2h2[k2];
        acc = fma2(splat2(r2[0].x), sW22[0 * 4 + k2], acc);
        acc = fma2(splat2(r2[0].y), sW22[1 * 4 + k2], acc);
        acc = fma2(splat2(r2[1].x), sW22[2 * 4 + k2], acc);
        acc = fma2(splat2(r2[1].y), sW22[3 * 4 + k2], acc);
        acc = fma2(splat2(r2[2].x), sW22[4 * 4 + k2], acc);
        acc = fma2(splat2(r2[2].y), sW22[5 * 4 + k2], acc);
        racc2[k2] = acc;
    }
}

__global__ __launch_bounds__(128) void omni_main(
    const float* __restrict__ dists_nuc,   // (B, NE, NA, DF)
    const float* __restrict__ dists_elec,  // (B, NE, NE, DF)
    const float* __restrict__ Y,           // (NA, KD)
    const float* __restrict__ w2,          // (2, 6, KD)
    const float* __restrict__ ws,          // precomputed constants
    float* __restrict__ out)               // (B,)
{
    const int tid  = threadIdx.x;
    const int h    = tid >> 6;          // wave: electrons of spin h
    const int lane = tid & 63;
    const int il   = lane & 15;
    const int jh   = lane >> 4;         // j quarter (j in [8jh, 8jh+8))
    const int ig   = 16 * h + il;       // this lane's electron
    const int b    = blockIdx.x;
    const int sj   = jh >> 1;           // spin of j range
    const bool same = (sj == h);
    const int t32  = same ? 0 : 32;

    // Per-lane LDS scratch for distance rows: written in n=0 (after first use),
    // re-read in n=1. Lane stride 16 B -> 2-way bank aliasing only (free).
    // This replaces both the R5 register cache (spilled to scratch: 49 MB) and
    // the R6 global re-read (100 MB FETCH, HBM-latency stalls).
    __shared__ float4 ebuf[8 * 128];    // [s][tid], 16 KB
    __shared__ float4 nbuf[2 * 128];    // [t][tid], 4 KB
    __shared__ float msg[65][KD];       // n=1 table; row 64 = zeros
    __shared__ float part[2];
    if (tid < KD) msg[64][tid] = 0.0f;

    const f32x2* ws2  = (const f32x2*)ws;
    const f32x2* w2p0 = (const f32x2*)w2;          // n=0: a*4+k2
    const f32x2* w2p1 = (const f32x2*)(w2 + 48);   // n=1
    const f32x2* Yp   = (const f32x2*)Y;

    const float* de = dists_elec + (((size_t)b * NE + ig) * NE + 8 * jh) * DF;
    const float* dn = dists_nuc  + (((size_t)b * NE + ig) * NA + 2 * jh) * DF;

    // =================== interaction 0 (no barrier) ===================
    float zr0[KD];
    {
        f32x2 vB1s2[3], vB2h2[4], msel2[4];
        #pragma unroll
        for (int a2 = 0; a2 < 3; ++a2) vB1s2[a2] = ws2[WS_B1S0 / 2 + a2];
        #pragma unroll
        for (int k2 = 0; k2 < 4; ++k2) vB2h2[k2] = ws2[WS_B2H0 / 2 + k2];
        #pragma unroll
        for (int k2 = 0; k2 < 4; ++k2)
            msel2[k2] = same ? ws2[WS_MS0 / 2 + k2] : ws2[WS_MA0 / 2 + k2];

        // factored electron part: z = msel * (S @ W2 + cnt*B2h)
        const int scnt  = ig - 8 * jh;
        const float fcnt = (jh == (ig >> 3)) ? 7.0f : 8.0f;
        f32x2 S2[3] = {splat2(0.f), splat2(0.f), splat2(0.f)};
        #pragma unroll
        for (int s = 0; s < 8; ++s) {
            const float4 e = ((const float4*)de)[s];
            ebuf[s * 128 + tid] = e;                 // stage for n=1
            f32x2 r2[3];
            wnet_r2(e, vB1s2, ws2 + WS_W1S0 / 2, r2);
            const float mf = (s == scnt) ? 0.0f : 1.0f;
            #pragma unroll
            for (int a2 = 0; a2 < 3; ++a2) S2[a2] = fma2(r2[a2], splat2(mf), S2[a2]);
        }
        f32x2 z2[4];
        #pragma unroll
        for (int k2 = 0; k2 < 4; ++k2) {
            f32x2 acc = splat2(fcnt) * vB2h2[k2];
            acc = fma2(splat2(S2[0].x), w2p0[0 * 4 + k2], acc);
            acc = fma2(splat2(S2[0].y), w2p0[1 * 4 + k2], acc);
            acc = fma2(splat2(S2[1].x), w2p0[2 * 4 + k2], acc);
            acc = fma2(splat2(S2[1].y), w2p0[3 * 4 + k2], acc);
            acc = fma2(splat2(S2[2].x), w2p0[4 * 4 + k2], acc);
            acc = fma2(splat2(S2[2].y), w2p0[5 * 4 + k2], acc);
            z2[k2] = acc * msel2[k2];
        }
        // nuclear part
        {
            const float4 f0 = ((const float4*)dn)[0];
            const float4 f1 = ((const float4*)dn)[1];
            nbuf[0 * 128 + tid] = f0;
            nbuf[1 * 128 + tid] = f1;
            f32x2 r2[3], racc2[4];
            wnet_r2(f0, vB1s2, ws2 + WS_W1S0 / 2, r2);
            proj2(r2, w2p0, vB2h2, racc2);
            #pragma unroll
            for (int k2 = 0; k2 < 4; ++k2)
                z2[k2] = fma2(racc2[k2], Yp[(2 * jh) * 4 + k2], z2[k2]);
            wnet_r2(f1, vB1s2, ws2 + WS_W1S0 / 2, r2);
            proj2(r2, w2p0, vB2h2, racc2);
            #pragma unroll
            for (int k2 = 0; k2 < 4; ++k2)
                z2[k2] = fma2(racc2[k2], Yp[(2 * jh + 1) * 4 + k2], z2[k2]);
        }
        #pragma unroll
        for (int k2 = 0; k2 < 4; ++k2) {
            float za = z2[k2].x, zb = z2[k2].y;
            za += __shfl_xor(za, 16, 64); za += __shfl_xor(za, 32, 64);
            zb += __shfl_xor(zb, 16, 64); zb += __shfl_xor(zb, 32, 64);
            zr0[2 * k2] = za; zr0[2 * k2 + 1] = zb;
        }
    }

    // =================== interaction 1 ===================
    // phase-1 via linearization: ms = Cs + zr0 @ Ms ; ma = Ca + zr0 @ Ma
    {
        f32x2 ms2[4], ma2[4];
        #pragma unroll
        for (int k2 = 0; k2 < 4; ++k2) {
            ms2[k2] = ws2[WS_CS / 2 + k2];
            ma2[k2] = ws2[WS_CA / 2 + k2];
        }
        #pragma unroll
        for (int kp = 0; kp < KD; ++kp) {
            const f32x2 zk = splat2(zr0[kp]);
            #pragma unroll
            for (int k2 = 0; k2 < 4; ++k2) {
                ms2[k2] = fma2(zk, ws2[WS_MS / 2 + kp * 4 + k2], ms2[k2]);
                ma2[k2] = fma2(zk, ws2[WS_MA / 2 + kp * 4 + k2], ma2[k2]);
            }
        }
        if (jh == 0) {
            #pragma unroll
            for (int k2 = 0; k2 < 4; ++k2) *(f32x2*)&msg[ig][2 * k2] = ms2[k2];
        } else if (jh == 2) {
            #pragma unroll
            for (int k2 = 0; k2 < 4; ++k2) *(f32x2*)&msg[32 + ig][2 * k2] = ma2[k2];
        }
        __syncthreads();
    }

    float zr1[KD];
    {
        f32x2 vB1s2[3], vB2h2[4];
        #pragma unroll
        for (int a2 = 0; a2 < 3; ++a2) vB1s2[a2] = ws2[WS_B1S1 / 2 + a2];
        #pragma unroll
        for (int k2 = 0; k2 < 4; ++k2) vB2h2[k2] = ws2[WS_B2H1 / 2 + k2];

        f32x2 z2[4] = {splat2(0.f), splat2(0.f), splat2(0.f), splat2(0.f)};
        #pragma unroll
        for (int s = 0; s < 8; ++s) {
            const float4 e = ebuf[s * 128 + tid];    // LDS re-read (own slot)
            f32x2 r2[3], racc2[4];
            wnet_r2(e, vB1s2, ws2 + WS_W1S1 / 2, r2);
            proj2(r2, w2p1, vB2h2, racc2);
            const int j = 8 * jh + s;
            const int row = (j == ig) ? 64 : (t32 + j);
            const f32x2* mrow = (const f32x2*)&msg[row][0];
            #pragma unroll
            for (int k2 = 0; k2 < 4; ++k2) z2[k2] = fma2(racc2[k2], mrow[k2], z2[k2]);
        }
        {
            const float4 f0 = nbuf[0 * 128 + tid];
            const float4 f1 = nbuf[1 * 128 + tid];
            f32x2 r2[3], racc2[4];
            wnet_r2(f0, vB1s2, ws2 + WS_W1S1 / 2, r2);
            proj2(r2, w2p1, vB2h2, racc2);
            #pragma unroll
            for (int k2 = 0; k2 < 4; ++k2)
                z2[k2] = fma2(racc2[k2], Yp[(2 * jh) * 4 + k2], z2[k2]);
            wnet_r2(f1, vB1s2, ws2 + WS_W1S1 / 2, r2);
            proj2(r2, w2p1, vB2h2, racc2);
            #pragma unroll
            for (int k2 = 0; k2 < 4; ++k2)
                z2[k2] = fma2(racc2[k2], Yp[(2 * jh + 1) * 4 + k2], z2[k2]);
        }
        #pragma unroll
        for (int k2 = 0; k2 < 4; ++k2) {
            float za = z2[k2].x, zb = z2[k2].y;
            za += __shfl_xor(za, 16, 64); za += __shfl_xor(za, 32, 64);
            zb += __shfl_xor(zb, 16, 64); zb += __shfl_xor(zb, 32, 64);
            zr1[2 * k2] = za; zr1[2 * k2 + 1] = zb;
        }
    }

    // =================== epilogue ===================
    float dot = 0.0f;
    #pragma unroll
    for (int k = 0; k < KD; ++k) dot = fmaf(zr0[k], ws[WS_GO0 + k], dot);
    #pragma unroll
    for (int k = 0; k < KD; ++k) dot = fmaf(zr1[k], ws[WS_GO1 + k], dot);
    dot += ws[WS_BASE];
    dot *= 0.25f;    // each electron replicated across 4 lanes
    #pragma unroll
    for (int off = 1; off < 64; off <<= 1) dot += __shfl_xor(dot, off, 64);
    if (lane == 0) part[h] = dot;
    __syncthreads();
    if (tid == 0) out[b] = part[0] + part[1];
}

extern "C" void kernel_launch(void* const* d_in, const int* in_sizes, int n_in,
                              void* d_out, int out_size, void* d_ws, size_t ws_size,
                              hipStream_t stream) {
    const float* dists_nuc  = (const float*)d_in[0];
    const float* dists_elec = (const float*)d_in[1];
    const float* X     = (const float*)d_in[2];
    const float* Y     = (const float*)d_in[3];
    const float* w1    = (const float*)d_in[4];
    const float* wb1   = (const float*)d_in[5];
    const float* w2    = (const float*)d_in[6];
    const float* wb2   = (const float*)d_in[7];
    const float* hs_w  = (const float*)d_in[8];
    const float* hs_b  = (const float*)d_in[9];
    const float* ha_w  = (const float*)d_in[10];
    const float* ha_b  = (const float*)d_in[11];
    const float* g_w   = (const float*)d_in[12];
    const float* g_b   = (const float*)d_in[13];
    const float* orb_w = (const float*)d_in[14];
    float* out = (float*)d_out;
    float* ws  = (float*)d_ws;

    omni_setup<<<1, 256, 0, stream>>>(X, w1, wb1, w2, wb2, hs_w, hs_b,
                                      ha_w, ha_b, g_w, g_b, orb_w, ws);
    omni_main<<<BATCH, 128, 0, stream>>>(dists_nuc, dists_elec, Y, w2, ws, out);
}